// Round 1
// 714.189 us; speedup vs baseline: 1.0741x; 1.0741x over previous
//
#include <hip/hip_runtime.h>

// Problem constants
#define N_NODES 100000
#define N_EDGES 3200000
#define IN_CH   256
#define OUT_CH  128

// Two-level counting-sort parameters
#define NGROUP     8                       // sublists per bucket (≈ XCD count)
#define BSH        6                       // bucket = src >> 6  (64 nodes)
#define BNODES     64
#define NBUCKET    1563                    // ceil(N_NODES / 64)
#define SUBL       (NBUCKET * NGROUP)      // 12504 stage-1 sublists
#define EPB        1024                    // edges per block (256 thr * 4)
#define NBLK_EDGE  (N_EDGES / EPB)         // 3125
#define SCAN_CH    49                      // ceil(SUBL / 256)

// ---------------------------------------------------------------------------
// Workspace layout (bytes):
//   xwb    [N_NODES*OUT_CH] bf16 : 25,600,000
//   wbf    [128][256]       bf16 :     65,536   (W^T, n-major)
//   cnt_b  [SUBL]           i32  :     50,016
//   rp_b   [SUBL+1(+pad)]   i32  :     50,048
//   cur_b  [SUBL]           i32  :     50,016
//   rpn    [N_NODES+1(+pad)]i32  :    400,016   (node-major CSR row ptrs)
//   p1     [N_EDGES]        int2 : 25,600,000   (bucket-sorted stage 1)
//   packed [N_EDGES]        int2 : 25,600,000   (node-sorted final CSR)
// total = 77,415,632  (ws_size >= 78,000,016 proven in R2)
// ---------------------------------------------------------------------------
#define OFF_XWB    0
#define OFF_WBF    25600000
#define OFF_CNTB   25665536
#define OFF_RPB    25715552
#define OFF_CURB   25765600
#define OFF_RPN    25815616
#define OFF_P1     26215632
#define OFF_PACKED 51815632

typedef __attribute__((ext_vector_type(8))) short    bf8;   // 8 bf16 = 4 VGPRs
typedef __attribute__((ext_vector_type(4))) float    f4;    // C/D frag
typedef __attribute__((ext_vector_type(4))) unsigned uv4;   // 16B load vehicle

__device__ __forceinline__ unsigned f2bf(float f) {   // fp32 -> bf16 (RNE)
    unsigned u = __float_as_uint(f);
    return (u + 0x7fffu + ((u >> 16) & 1u)) >> 16;
}

// ---------------------------------------------------------------------------
// W^T conversion: w[256][128] fp32 -> wbf[128][256] bf16 (n-major).
// ---------------------------------------------------------------------------
__global__ __launch_bounds__(256) void wcvt_kernel(const float* __restrict__ w,
                                                   unsigned short* __restrict__ wbf) {
    int t = threadIdx.x;
    int k = blockIdx.x * 2 + (t >> 7);
    int n = t & 127;
    wbf[n * 256 + k] = (unsigned short)f2bf(w[k * 128 + n]);
}

// ---------------------------------------------------------------------------
// MFMA GEMM: xw = x @ W (bf16 inputs, fp32 accumulate, bf16 output).
// Wave tile = 16 rows x 128 cols (8 col-tiles of mfma_f32_16x16x32_bf16).
// ---------------------------------------------------------------------------
__global__ __launch_bounds__(256) void gemm_kernel(const float* __restrict__ x,
                                                   const unsigned short* __restrict__ wbf,
                                                   unsigned* __restrict__ xwb) {
    int wave = threadIdx.x >> 6;
    int lane = threadIdx.x & 63;
    int m = lane & 15;
    int q = lane >> 4;
    int r0 = blockIdx.x * 64 + wave * 16;

    int arow = r0 + m;
    if (arow >= N_NODES) arow = N_NODES - 1;     // clamp loads; stores guarded
    const float* xr = x + (long long)arow * IN_CH + q * 8;

    f4 acc[8];
#pragma unroll
    for (int ct = 0; ct < 8; ++ct) acc[ct] = (f4){0.f, 0.f, 0.f, 0.f};

#pragma unroll
    for (int ks = 0; ks < 8; ++ks) {             // k0 = ks*32
        float4 xa = *(const float4*)(xr + ks * 32);
        float4 xb = *(const float4*)(xr + ks * 32 + 4);
        bf8 a;
        a[0] = (short)f2bf(xa.x); a[1] = (short)f2bf(xa.y);
        a[2] = (short)f2bf(xa.z); a[3] = (short)f2bf(xa.w);
        a[4] = (short)f2bf(xb.x); a[5] = (short)f2bf(xb.y);
        a[6] = (short)f2bf(xb.z); a[7] = (short)f2bf(xb.w);
#pragma unroll
        for (int ct = 0; ct < 8; ++ct) {
            uv4 u = *(const uv4*)&wbf[(ct * 16 + m) * 256 + ks * 32 + q * 8];
            bf8 b = __builtin_bit_cast(bf8, u);
            acc[ct] = __builtin_amdgcn_mfma_f32_16x16x32_bf16(a, b, acc[ct], 0, 0, 0);
        }
    }

#pragma unroll
    for (int ct = 0; ct < 8; ++ct) {
#pragma unroll
        for (int r = 0; r < 4; ++r) {
            float v = acc[ct][r];
            float p = __shfl_xor(v, 1, 64);
            unsigned mine = f2bf(v), oth = f2bf(p);
            if (!(m & 1)) {
                int row = r0 + q * 4 + r;
                if (row < N_NODES)
                    xwb[row * 64 + ct * 8 + (m >> 1)] = mine | (oth << 16);
            }
        }
    }
}

// ---------------------------------------------------------------------------
// Stage-0: zero the stage-1 sublist counters (12,504 ints)
// ---------------------------------------------------------------------------
__global__ __launch_bounds__(256) void zero_b(int* __restrict__ cnt) {
    int i = (blockIdx.x * 256 + threadIdx.x) * 4;
    if (i < SUBL) *(int4*)&cnt[i] = make_int4(0, 0, 0, 0);
}

// ---------------------------------------------------------------------------
// Stage-1 histogram: count edges per (bucket, group).
// 12,504 counters -> ~256 atomics/address, negligible contention.
// ---------------------------------------------------------------------------
__global__ __launch_bounds__(256) void hist_b(const int* __restrict__ src,
                                              int* __restrict__ cnt) {
    int g  = blockIdx.x & (NGROUP - 1);
    int e0 = blockIdx.x * EPB + threadIdx.x * 4;
    int4 s = *(const int4*)&src[e0];
    atomicAdd(&cnt[(s.x >> BSH) * NGROUP + g], 1);
    atomicAdd(&cnt[(s.y >> BSH) * NGROUP + g], 1);
    atomicAdd(&cnt[(s.z >> BSH) * NGROUP + g], 1);
    atomicAdd(&cnt[(s.w >> BSH) * NGROUP + g], 1);
}

// ---------------------------------------------------------------------------
// Single-block exclusive scan over SUBL=12,504 counts -> rp_b, cur_b.
// Also seeds rpn[N_NODES] = N_EDGES.
// ---------------------------------------------------------------------------
__global__ __launch_bounds__(256) void scan_b(const int* __restrict__ cnt,
                                              int* __restrict__ rp,
                                              int* __restrict__ cur,
                                              int* __restrict__ rpn) {
    __shared__ int woff[4];
    int tid = threadIdx.x, lane = tid & 63, wid = tid >> 6;
    int base = tid * SCAN_CH;
    int s = 0;
#pragma unroll
    for (int k = 0; k < SCAN_CH; ++k) {
        int i = base + k;
        if (i < SUBL) s += cnt[i];
    }
    int v = s;
#pragma unroll
    for (int off = 1; off < 64; off <<= 1) {
        int t = __shfl_up(v, off, 64);
        if (lane >= off) v += t;
    }
    if (lane == 63) woff[wid] = v;
    __syncthreads();
    int add = (wid > 0 ? woff[0] : 0) + (wid > 1 ? woff[1] : 0) + (wid > 2 ? woff[2] : 0);
    int run = add + v - s;                      // exclusive prefix of this chunk
    for (int k = 0; k < SCAN_CH; ++k) {
        int i = base + k;
        if (i < SUBL) {
            int c = cnt[i];
            rp[i] = run;
            cur[i] = run;
            run += c;
        }
    }
    if (tid == 255) { rp[SUBL] = run; rpn[N_NODES] = run; }   // == N_EDGES
}

// ---------------------------------------------------------------------------
// Stage-1 scatter into coarse buckets. Write frontier = 12,504 lines
// (~800 KB) -> L2-resident -> each 64B line filled before eviction
// (vs 51 MB frontier / 10x amplification in the old per-node scatter).
// Record: x = dst | (src&63)<<17   (dst < 2^17), y = val bits.
// ---------------------------------------------------------------------------
__global__ __launch_bounds__(256) void build1(const int* __restrict__ src,
                                              const int* __restrict__ dst,
                                              const float* __restrict__ val,
                                              int* __restrict__ cursor,
                                              int2* __restrict__ p1) {
    int g  = blockIdx.x & (NGROUP - 1);
    int e0 = blockIdx.x * EPB + threadIdx.x * 4;
    int4   s = *(const int4*)&src[e0];
    int4   d = *(const int4*)&dst[e0];
    float4 v = *(const float4*)&val[e0];
    int p;
    p = atomicAdd(&cursor[(s.x >> BSH) * NGROUP + g], 1);
    p1[p] = make_int2(d.x | ((s.x & (BNODES - 1)) << 17), __float_as_int(v.x));
    p = atomicAdd(&cursor[(s.y >> BSH) * NGROUP + g], 1);
    p1[p] = make_int2(d.y | ((s.y & (BNODES - 1)) << 17), __float_as_int(v.y));
    p = atomicAdd(&cursor[(s.z >> BSH) * NGROUP + g], 1);
    p1[p] = make_int2(d.z | ((s.z & (BNODES - 1)) << 17), __float_as_int(v.z));
    p = atomicAdd(&cursor[(s.w >> BSH) * NGROUP + g], 1);
    p1[p] = make_int2(d.w | ((s.w & (BNODES - 1)) << 17), __float_as_int(v.w));
}

// ---------------------------------------------------------------------------
// Stage-2: one block per bucket. LDS 64-bin hist + wave scan, then scatter
// the bucket's ~2048 edges to final node-major CSR positions — a contiguous
// ~16 KB segment owned by this block (streaming, no amplification).
// Emits rpn[] (per-node row pointers) for free.
// ---------------------------------------------------------------------------
__global__ __launch_bounds__(256) void sort2(const int2* __restrict__ p1,
                                             const int* __restrict__ rp_b,
                                             int2* __restrict__ packed,
                                             int* __restrict__ rpn) {
    __shared__ int lcnt[BNODES];
    __shared__ int lcur[BNODES];
    int b = blockIdx.x, tid = threadIdx.x;
    int beg = rp_b[b * NGROUP];
    int end = rp_b[b * NGROUP + NGROUP];

    if (tid < BNODES) lcnt[tid] = 0;
    __syncthreads();

    for (int e = beg + tid; e < end; e += 256) {
        int x = p1[e].x;
        atomicAdd(&lcnt[(x >> 17) & (BNODES - 1)], 1);
    }
    __syncthreads();

    if (tid < BNODES) {                          // wave 0: scan 64 counts
        int c = lcnt[tid];
        int v = c;
#pragma unroll
        for (int off = 1; off < 64; off <<= 1) {
            int t = __shfl_up(v, off, 64);
            if (tid >= off) v += t;
        }
        int excl = beg + v - c;
        lcur[tid] = excl;
        int node = b * BNODES + tid;
        if (node < N_NODES) rpn[node] = excl;
    }
    __syncthreads();

    for (int e = beg + tid; e < end; e += 256) {
        int2 q = p1[e];
        int p = atomicAdd(&lcur[(q.x >> 17) & (BNODES - 1)], 1);
        packed[p] = make_int2(q.x & 0x1FFFF, q.y);
    }
}

// ---------------------------------------------------------------------------
// Aggregate: one node per wave; node-major CSR (one contiguous run/node).
// bf16x2 gathers, fp32 accumulate.
// ---------------------------------------------------------------------------
__global__ __launch_bounds__(256) void aggregate_kernel(const int* __restrict__ rp,
                                                        const int2* __restrict__ packed,
                                                        const unsigned* __restrict__ xwb,
                                                        const float* __restrict__ bias,
                                                        float* __restrict__ out) {
    int node = blockIdx.x * 4 + (threadIdx.x >> 6);
    int lane = threadIdx.x & 63;
    float2 acc = *(const float2*)&bias[lane * 2];

    int e   = rp[node];
    int end = rp[node + 1];
    for (; e + 4 <= end; e += 4) {
        int2 p0 = packed[e + 0];
        int2 p1 = packed[e + 1];
        int2 p2 = packed[e + 2];
        int2 p3 = packed[e + 3];
        unsigned u0 = xwb[p0.x * 64 + lane];
        unsigned u1 = xwb[p1.x * 64 + lane];
        unsigned u2 = xwb[p2.x * 64 + lane];
        unsigned u3 = xwb[p3.x * 64 + lane];
        float v0 = __int_as_float(p0.y), v1 = __int_as_float(p1.y);
        float v2 = __int_as_float(p2.y), v3 = __int_as_float(p3.y);
        acc.x += v0 * __uint_as_float(u0 << 16);
        acc.y += v0 * __uint_as_float(u0 & 0xffff0000u);
        acc.x += v1 * __uint_as_float(u1 << 16);
        acc.y += v1 * __uint_as_float(u1 & 0xffff0000u);
        acc.x += v2 * __uint_as_float(u2 << 16);
        acc.y += v2 * __uint_as_float(u2 & 0xffff0000u);
        acc.x += v3 * __uint_as_float(u3 << 16);
        acc.y += v3 * __uint_as_float(u3 & 0xffff0000u);
    }
    for (; e < end; ++e) {
        int2 p = packed[e];
        unsigned u = xwb[p.x * 64 + lane];
        float v = __int_as_float(p.y);
        acc.x += v * __uint_as_float(u << 16);
        acc.y += v * __uint_as_float(u & 0xffff0000u);
    }
    *(float2*)&out[(long long)node * OUT_CH + lane * 2] = acc;
}

extern "C" void kernel_launch(void* const* d_in, const int* in_sizes, int n_in,
                              void* d_out, int out_size, void* d_ws, size_t ws_size,
                              hipStream_t stream) {
    const float* x     = (const float*)d_in[0];
    const int*   esrc  = (const int*)d_in[1];
    const int*   edst  = (const int*)d_in[2];
    const float* evals = (const float*)d_in[3];
    const float* w     = (const float*)d_in[4];
    const float* bias  = (const float*)d_in[5];
    float* out = (float*)d_out;

    char* ws = (char*)d_ws;
    unsigned*       xwb    = (unsigned*)      (ws + OFF_XWB);
    unsigned short* wbf    = (unsigned short*)(ws + OFF_WBF);
    int*            cnt_b  = (int*)           (ws + OFF_CNTB);
    int*            rp_b   = (int*)           (ws + OFF_RPB);
    int*            cur_b  = (int*)           (ws + OFF_CURB);
    int*            rpn    = (int*)           (ws + OFF_RPN);
    int2*           p1     = (int2*)          (ws + OFF_P1);
    int2*           packed = (int2*)          (ws + OFF_PACKED);

    wcvt_kernel<<<128, 256, 0, stream>>>(w, wbf);
    gemm_kernel<<<(N_NODES + 63) / 64, 256, 0, stream>>>(x, wbf, xwb);
    zero_b<<<(SUBL / 4 + 255) / 256, 256, 0, stream>>>(cnt_b);
    hist_b<<<NBLK_EDGE, 256, 0, stream>>>(esrc, cnt_b);
    scan_b<<<1, 256, 0, stream>>>(cnt_b, rp_b, cur_b, rpn);
    build1<<<NBLK_EDGE, 256, 0, stream>>>(esrc, edst, evals, cur_b, p1);
    sort2<<<NBUCKET, 256, 0, stream>>>(p1, rp_b, packed, rpn);
    aggregate_kernel<<<N_NODES / 4, 256, 0, stream>>>(rpn, packed, xwb, bias, out);
}

// Round 2
// 451.809 us; speedup vs baseline: 1.6979x; 1.5807x over previous
//
#include <hip/hip_runtime.h>

// Problem constants
#define N_NODES 100000
#define N_EDGES 3200000
#define IN_CH   256
#define OUT_CH  128

// Deterministic two-pass counting sort (NO device-scope atomics anywhere).
#define BSH        5                        // bucket = src >> 5  (32 nodes)
#define BN         32                       // nodes per bucket
#define NBIN       3125                     // N_NODES / BN (exact)
#define NBLK1      392                      // stage-1 chunks (1024-thr blocks)
#define EPB1       8192                     // edges per stage-1 chunk (last partial)
#define NS1        (NBIN * NBLK1)           // 1,225,000 counters (div by 4)
#define SCAN_CHUNK 8192
#define NBLK_S1    ((NS1 + SCAN_CHUNK - 1) / SCAN_CHUNK)   // 150

// ---------------------------------------------------------------------------
// Workspace layout (bytes):
//   xwb    [N_NODES*OUT_CH] bf16 : 25,600,000
//   wbf    [128][256]       bf16 :     65,536   (W^T, n-major)
//   cntA   [NBIN][NBLK1]    i32  :  4,900,000   (per-bucket, per-chunk counts)
//   rpA    [NS1+1(+pad)]    i32  :  4,900,016   (scanned bases, bucket-major)
//   bsum   [256]            i32  :      1,024
//   rpn    [N_NODES+1(+pad)]i32  :    400,016   (node-major CSR row ptrs)
//   packed [N_EDGES]        int2 : 25,600,000   (node-sorted final CSR)
// total = 61,466,592  (ws_size >= 78,000,016 proven in R2)
// p1 (bucket-sorted stage-1 records, 25.6 MB) lives in d_out (51.2 MB) —
// d_out is dead until aggregate_kernel, which fully overwrites it.
// ---------------------------------------------------------------------------
#define OFF_XWB    0
#define OFF_WBF    25600000
#define OFF_CNTA   25665536
#define OFF_RPA    30565536
#define OFF_BS     35465552
#define OFF_RPN    35466576
#define OFF_PACKED 35866592

typedef __attribute__((ext_vector_type(8))) short    bf8;   // 8 bf16 = 4 VGPRs
typedef __attribute__((ext_vector_type(4))) float    f4;    // C/D frag
typedef __attribute__((ext_vector_type(4))) unsigned uv4;   // 16B load vehicle

__device__ __forceinline__ unsigned f2bf(float f) {   // fp32 -> bf16 (RNE)
    unsigned u = __float_as_uint(f);
    return (u + 0x7fffu + ((u >> 16) & 1u)) >> 16;
}

// ---------------------------------------------------------------------------
// W^T conversion: w[256][128] fp32 -> wbf[128][256] bf16 (n-major).
// ---------------------------------------------------------------------------
__global__ __launch_bounds__(256) void wcvt_kernel(const float* __restrict__ w,
                                                   unsigned short* __restrict__ wbf) {
    int t = threadIdx.x;
    int k = blockIdx.x * 2 + (t >> 7);
    int n = t & 127;
    wbf[n * 256 + k] = (unsigned short)f2bf(w[k * 128 + n]);
}

// ---------------------------------------------------------------------------
// MFMA GEMM: xw = x @ W (bf16 inputs, fp32 accumulate, bf16 output).
// Wave tile = 16 rows x 128 cols (8 col-tiles of mfma_f32_16x16x32_bf16).
// ---------------------------------------------------------------------------
__global__ __launch_bounds__(256) void gemm_kernel(const float* __restrict__ x,
                                                   const unsigned short* __restrict__ wbf,
                                                   unsigned* __restrict__ xwb) {
    int wave = threadIdx.x >> 6;
    int lane = threadIdx.x & 63;
    int m = lane & 15;
    int q = lane >> 4;
    int r0 = blockIdx.x * 64 + wave * 16;

    int arow = r0 + m;
    if (arow >= N_NODES) arow = N_NODES - 1;     // clamp loads; stores guarded
    const float* xr = x + (long long)arow * IN_CH + q * 8;

    f4 acc[8];
#pragma unroll
    for (int ct = 0; ct < 8; ++ct) acc[ct] = (f4){0.f, 0.f, 0.f, 0.f};

#pragma unroll
    for (int ks = 0; ks < 8; ++ks) {             // k0 = ks*32
        float4 xa = *(const float4*)(xr + ks * 32);
        float4 xb = *(const float4*)(xr + ks * 32 + 4);
        bf8 a;
        a[0] = (short)f2bf(xa.x); a[1] = (short)f2bf(xa.y);
        a[2] = (short)f2bf(xa.z); a[3] = (short)f2bf(xa.w);
        a[4] = (short)f2bf(xb.x); a[5] = (short)f2bf(xb.y);
        a[6] = (short)f2bf(xb.z); a[7] = (short)f2bf(xb.w);
#pragma unroll
        for (int ct = 0; ct < 8; ++ct) {
            uv4 u = *(const uv4*)&wbf[(ct * 16 + m) * 256 + ks * 32 + q * 8];
            bf8 b = __builtin_bit_cast(bf8, u);
            acc[ct] = __builtin_amdgcn_mfma_f32_16x16x32_bf16(a, b, acc[ct], 0, 0, 0);
        }
    }

#pragma unroll
    for (int ct = 0; ct < 8; ++ct) {
#pragma unroll
        for (int r = 0; r < 4; ++r) {
            float v = acc[ct][r];
            float p = __shfl_xor(v, 1, 64);
            unsigned mine = f2bf(v), oth = f2bf(p);
            if (!(m & 1)) {
                int row = r0 + q * 4 + r;
                if (row < N_NODES)
                    xwb[row * 64 + ct * 8 + (m >> 1)] = mine | (oth << 16);
            }
        }
    }
}

// ---------------------------------------------------------------------------
// Stage-1 histogram: per-chunk LDS histogram over 3125 buckets; LDS atomics
// only. Writes cntA[bucket][chunk] (bucket-major so the scan is linear).
// ---------------------------------------------------------------------------
__global__ __launch_bounds__(1024) void h1_kernel(const int* __restrict__ src,
                                                  int* __restrict__ cntA) {
    __shared__ int lc[NBIN];
    int tid = threadIdx.x;
    for (int i = tid; i < NBIN; i += 1024) lc[i] = 0;
    __syncthreads();
#pragma unroll
    for (int k = 0; k < EPB1 / 4096; ++k) {
        int i = blockIdx.x * EPB1 + k * 4096 + tid * 4;
        if (i < N_EDGES) {                       // i,N_EDGES both mult of 4
            int4 s = *(const int4*)&src[i];
            atomicAdd(&lc[s.x >> BSH], 1);
            atomicAdd(&lc[s.y >> BSH], 1);
            atomicAdd(&lc[s.z >> BSH], 1);
            atomicAdd(&lc[s.w >> BSH], 1);
        }
    }
    __syncthreads();
    for (int i = tid; i < NBIN; i += 1024)
        cntA[i * NBLK1 + blockIdx.x] = lc[i];
}

// ---------------------------------------------------------------------------
// 3-kernel exclusive scan over NS1 = 1,225,000 counts -> rpA (same order).
// ---------------------------------------------------------------------------
__global__ __launch_bounds__(256) void scan_s1(const int* __restrict__ cnt,
                                               int* __restrict__ bsum) {
    __shared__ int wsum[4];
    int tid = threadIdx.x, lane = tid & 63, wid = tid >> 6;
    int acc = 0;
#pragma unroll
    for (int k = 0; k < SCAN_CHUNK / 1024; ++k) {
        int i0 = blockIdx.x * SCAN_CHUNK + k * 1024 + tid * 4;
        if (i0 < NS1) {                          // NS1 mult of 4 -> full int4 ok
            int4 v = *(const int4*)&cnt[i0];
            acc += v.x + v.y + v.z + v.w;
        }
    }
#pragma unroll
    for (int off = 32; off; off >>= 1) acc += __shfl_down(acc, off, 64);
    if (lane == 0) wsum[wid] = acc;
    __syncthreads();
    if (tid == 0) bsum[blockIdx.x] = wsum[0] + wsum[1] + wsum[2] + wsum[3];
}

__global__ __launch_bounds__(256) void scan_s2(int* __restrict__ bsum,
                                               int* __restrict__ rpA,
                                               int* __restrict__ rpn) {
    __shared__ int wsum[4];
    int tid = threadIdx.x, lane = tid & 63, wid = tid >> 6;
    int v = (tid < NBLK_S1) ? bsum[tid] : 0;
    int s = v;
#pragma unroll
    for (int off = 1; off < 64; off <<= 1) {
        int t = __shfl_up(s, off, 64);
        if (lane >= off) s += t;
    }
    if (lane == 63) wsum[wid] = s;
    __syncthreads();
    int w0 = wsum[0], w1 = wsum[1], w2 = wsum[2], w3 = wsum[3];
    int woff = (wid > 0 ? w0 : 0) + (wid > 1 ? w1 : 0) + (wid > 2 ? w2 : 0);
    if (tid < NBLK_S1) bsum[tid] = woff + s - v;
    if (tid == 0) {
        int tot = w0 + w1 + w2 + w3;             // == N_EDGES
        rpA[NS1] = tot;
        rpn[N_NODES] = tot;
    }
}

__global__ __launch_bounds__(256) void scan_s3(const int* __restrict__ cnt,
                                               const int* __restrict__ bsum,
                                               int* __restrict__ rpA) {
    __shared__ int wsum[4];
    int tid = threadIdx.x, lane = tid & 63, wid = tid >> 6;
    int carry = bsum[blockIdx.x];
#pragma unroll
    for (int k = 0; k < SCAN_CHUNK / 1024; ++k) {
        int i0 = blockIdx.x * SCAN_CHUNK + k * 1024 + tid * 4;
        int4 v = make_int4(0, 0, 0, 0);
        if (i0 < NS1) v = *(const int4*)&cnt[i0];
        int sum4 = v.x + v.y + v.z + v.w;
        int s = sum4;
#pragma unroll
        for (int off = 1; off < 64; off <<= 1) {
            int t = __shfl_up(s, off, 64);
            if (lane >= off) s += t;
        }
        if (lane == 63) wsum[wid] = s;
        __syncthreads();
        int w0 = wsum[0], w1 = wsum[1], w2 = wsum[2], w3 = wsum[3];
        int woff = (wid > 0 ? w0 : 0) + (wid > 1 ? w1 : 0) + (wid > 2 ? w2 : 0);
        int excl = carry + woff + (s - sum4);
        if (i0 < NS1)
            *(int4*)&rpA[i0] = make_int4(excl, excl + v.x, excl + v.x + v.y,
                                         excl + v.x + v.y + v.z);
        carry += w0 + w1 + w2 + w3;
        __syncthreads();
    }
}

// ---------------------------------------------------------------------------
// Stage-1 scatter, deterministic bases: each chunk loads its per-bucket base
// offsets into LDS, ranks edges with LDS atomicAdd, stores records to its
// private (bucket,chunk) segments. Zero device atomics; writes ~1x payload.
// Record: x = dst | (src&31)<<17   (dst < 2^17), y = val bits.
// ---------------------------------------------------------------------------
__global__ __launch_bounds__(1024) void b1_kernel(const int* __restrict__ src,
                                                  const int* __restrict__ dst,
                                                  const float* __restrict__ val,
                                                  const int* __restrict__ rpA,
                                                  int2* __restrict__ p1) {
    __shared__ int lcur[NBIN];
    int tid = threadIdx.x;
    for (int i = tid; i < NBIN; i += 1024)
        lcur[i] = rpA[i * NBLK1 + blockIdx.x];
    __syncthreads();
#pragma unroll
    for (int k = 0; k < EPB1 / 4096; ++k) {
        int i = blockIdx.x * EPB1 + k * 4096 + tid * 4;
        if (i < N_EDGES) {
            int4   s = *(const int4*)&src[i];
            int4   d = *(const int4*)&dst[i];
            float4 v = *(const float4*)&val[i];
            int p;
            p = atomicAdd(&lcur[s.x >> BSH], 1);
            p1[p] = make_int2(d.x | ((s.x & (BN - 1)) << 17), __float_as_int(v.x));
            p = atomicAdd(&lcur[s.y >> BSH], 1);
            p1[p] = make_int2(d.y | ((s.y & (BN - 1)) << 17), __float_as_int(v.y));
            p = atomicAdd(&lcur[s.z >> BSH], 1);
            p1[p] = make_int2(d.z | ((s.z & (BN - 1)) << 17), __float_as_int(v.z));
            p = atomicAdd(&lcur[s.w >> BSH], 1);
            p1[p] = make_int2(d.w | ((s.w & (BN - 1)) << 17), __float_as_int(v.w));
        }
    }
}

// ---------------------------------------------------------------------------
// Stage-2: one block per 32-node bucket. LDS 32-bin hist + wave scan, then
// scatter the bucket's ~1024 edges to final node-major CSR positions — a
// contiguous ~8 KB segment owned by this block. Emits rpn[] for free.
// ---------------------------------------------------------------------------
__global__ __launch_bounds__(256) void sortf_kernel(const int2* __restrict__ p1,
                                                    const int* __restrict__ rpA,
                                                    int2* __restrict__ packed,
                                                    int* __restrict__ rpn) {
    __shared__ int lcnt[BN];
    __shared__ int lcur[BN];
    int b = blockIdx.x, tid = threadIdx.x;
    int beg = rpA[b * NBLK1];
    int end = rpA[(b + 1) * NBLK1];              // b==NBIN-1 hits rpA[NS1]

    if (tid < BN) lcnt[tid] = 0;
    __syncthreads();

    for (int e = beg + tid; e < end; e += 256)
        atomicAdd(&lcnt[(p1[e].x >> 17) & (BN - 1)], 1);
    __syncthreads();

    if (tid < BN) {                              // wave 0: scan 32 counts
        int c = lcnt[tid];
        int v = c;
#pragma unroll
        for (int off = 1; off < BN; off <<= 1) {
            int t = __shfl_up(v, off, 64);
            if (tid >= off) v += t;
        }
        int excl = beg + v - c;
        lcur[tid] = excl;
        rpn[b * BN + tid] = excl;                // NBIN*BN == N_NODES exactly
    }
    __syncthreads();

    for (int e = beg + tid; e < end; e += 256) {
        int2 q = p1[e];
        int p = atomicAdd(&lcur[(q.x >> 17) & (BN - 1)], 1);
        packed[p] = make_int2(q.x & 0x1FFFF, q.y);
    }
}

// ---------------------------------------------------------------------------
// Aggregate: one node per wave; node-major CSR (one contiguous run/node).
// bf16x2 gathers, fp32 accumulate.
// ---------------------------------------------------------------------------
__global__ __launch_bounds__(256) void aggregate_kernel(const int* __restrict__ rp,
                                                        const int2* __restrict__ packed,
                                                        const unsigned* __restrict__ xwb,
                                                        const float* __restrict__ bias,
                                                        float* __restrict__ out) {
    int node = blockIdx.x * 4 + (threadIdx.x >> 6);
    int lane = threadIdx.x & 63;
    float2 acc = *(const float2*)&bias[lane * 2];

    int e   = rp[node];
    int end = rp[node + 1];
    for (; e + 4 <= end; e += 4) {
        int2 p0 = packed[e + 0];
        int2 p1 = packed[e + 1];
        int2 p2 = packed[e + 2];
        int2 p3 = packed[e + 3];
        unsigned u0 = xwb[p0.x * 64 + lane];
        unsigned u1 = xwb[p1.x * 64 + lane];
        unsigned u2 = xwb[p2.x * 64 + lane];
        unsigned u3 = xwb[p3.x * 64 + lane];
        float v0 = __int_as_float(p0.y), v1 = __int_as_float(p1.y);
        float v2 = __int_as_float(p2.y), v3 = __int_as_float(p3.y);
        acc.x += v0 * __uint_as_float(u0 << 16);
        acc.y += v0 * __uint_as_float(u0 & 0xffff0000u);
        acc.x += v1 * __uint_as_float(u1 << 16);
        acc.y += v1 * __uint_as_float(u1 & 0xffff0000u);
        acc.x += v2 * __uint_as_float(u2 << 16);
        acc.y += v2 * __uint_as_float(u2 & 0xffff0000u);
        acc.x += v3 * __uint_as_float(u3 << 16);
        acc.y += v3 * __uint_as_float(u3 & 0xffff0000u);
    }
    for (; e < end; ++e) {
        int2 p = packed[e];
        unsigned u = xwb[p.x * 64 + lane];
        float v = __int_as_float(p.y);
        acc.x += v * __uint_as_float(u << 16);
        acc.y += v * __uint_as_float(u & 0xffff0000u);
    }
    *(float2*)&out[(long long)node * OUT_CH + lane * 2] = acc;
}

extern "C" void kernel_launch(void* const* d_in, const int* in_sizes, int n_in,
                              void* d_out, int out_size, void* d_ws, size_t ws_size,
                              hipStream_t stream) {
    const float* x     = (const float*)d_in[0];
    const int*   esrc  = (const int*)d_in[1];
    const int*   edst  = (const int*)d_in[2];
    const float* evals = (const float*)d_in[3];
    const float* w     = (const float*)d_in[4];
    const float* bias  = (const float*)d_in[5];
    float* out = (float*)d_out;

    char* ws = (char*)d_ws;
    unsigned*       xwb    = (unsigned*)      (ws + OFF_XWB);
    unsigned short* wbf    = (unsigned short*)(ws + OFF_WBF);
    int*            cntA   = (int*)           (ws + OFF_CNTA);
    int*            rpA    = (int*)           (ws + OFF_RPA);
    int*            bsum   = (int*)           (ws + OFF_BS);
    int*            rpn    = (int*)           (ws + OFF_RPN);
    int2*           packed = (int2*)          (ws + OFF_PACKED);
    int2*           p1     = (int2*)          d_out;   // scratch; dead before aggregate

    wcvt_kernel<<<128, 256, 0, stream>>>(w, wbf);
    gemm_kernel<<<(N_NODES + 63) / 64, 256, 0, stream>>>(x, wbf, xwb);
    h1_kernel<<<NBLK1, 1024, 0, stream>>>(esrc, cntA);
    scan_s1<<<NBLK_S1, 256, 0, stream>>>(cntA, bsum);
    scan_s2<<<1, 256, 0, stream>>>(bsum, rpA, rpn);
    scan_s3<<<NBLK_S1, 256, 0, stream>>>(cntA, bsum, rpA);
    b1_kernel<<<NBLK1, 1024, 0, stream>>>(esrc, edst, evals, rpA, p1);
    sortf_kernel<<<NBIN, 256, 0, stream>>>(p1, rpA, packed, rpn);
    aggregate_kernel<<<N_NODES / 4, 256, 0, stream>>>(rpn, packed, xwb, bias, out);
}

// Round 3
// 430.040 us; speedup vs baseline: 1.7838x; 1.0506x over previous
//
#include <hip/hip_runtime.h>

// Problem constants
#define N_NODES 100000
#define N_EDGES 3200000
#define IN_CH   256
#define OUT_CH  128

// Deterministic two-pass counting sort (NO device-scope atomics anywhere).
#define BSH        5                        // bucket = src >> 5  (32 nodes)
#define BN         32                       // nodes per bucket
#define NBIN       3125                     // N_NODES / BN (exact)
#define NBLK1      392                      // stage-1 chunks (1024-thr blocks)
#define EPB1       8192                     // edges per stage-1 chunk (last partial)
#define NS1        (NBIN * NBLK1)           // 1,225,000 counters (div by 4)
#define SCAN_CHUNK 8192
#define NBLK_S1    ((NS1 + SCAN_CHUNK - 1) / SCAN_CHUNK)   // 150
#define SCAP       2048                     // sortf LDS staging capacity (records)

// ---------------------------------------------------------------------------
// Workspace layout (bytes):
//   xwb    [N_NODES*OUT_CH] bf16 : 25,600,000
//   wbf    [128][256]       bf16 :     65,536   (W^T, n-major)
//   cntT   [NBLK1][NBIN]    i32  :  4,900,000   (chunk-major counts, coalesced h1)
//   cntA   [NBIN][NBLK1]    i32  :  4,900,000   (bucket-major, scan order)
//   rpA    [NS1+1(+pad)]    i32  :  4,900,016   (scanned bases, bucket-major)
//   rpT    [NBLK1][NBIN]    i32  :  4,900,000   (bases, chunk-major for b1)
//   bsum   [256]            i32  :      1,024
//   rpn    [N_NODES+1(+pad)]i32  :    400,016   (node-major CSR row ptrs)
//   packed [N_EDGES]        int2 : 25,600,000   (node-sorted final CSR)
// total = 71,266,592  (ws_size >= 78,000,016 proven in R2)
// p1 (bucket-sorted stage-1 records, 25.6 MB) lives in d_out (51.2 MB) —
// dead before aggregate_kernel, which fully overwrites d_out.
// ---------------------------------------------------------------------------
#define OFF_XWB    0
#define OFF_WBF    25600000
#define OFF_CNTT   25665536
#define OFF_CNTA   30565536
#define OFF_RPA    35465536
#define OFF_RPT    40365552
#define OFF_BS     45265552
#define OFF_RPN    45266576
#define OFF_PACKED 45666592

typedef __attribute__((ext_vector_type(8))) short    bf8;   // 8 bf16 = 4 VGPRs
typedef __attribute__((ext_vector_type(4))) float    f4;    // C/D frag
typedef __attribute__((ext_vector_type(4))) unsigned uv4;   // 16B load vehicle

__device__ __forceinline__ unsigned f2bf(float f) {   // fp32 -> bf16 (RNE)
    unsigned u = __float_as_uint(f);
    return (u + 0x7fffu + ((u >> 16) & 1u)) >> 16;
}

// ---------------------------------------------------------------------------
// W^T conversion: w[256][128] fp32 -> wbf[128][256] bf16 (n-major).
// ---------------------------------------------------------------------------
__global__ __launch_bounds__(256) void wcvt_kernel(const float* __restrict__ w,
                                                   unsigned short* __restrict__ wbf) {
    int t = threadIdx.x;
    int k = blockIdx.x * 2 + (t >> 7);
    int n = t & 127;
    wbf[n * 256 + k] = (unsigned short)f2bf(w[k * 128 + n]);
}

// ---------------------------------------------------------------------------
// MFMA GEMM: xw = x @ W (bf16 inputs, fp32 accumulate, bf16 output).
// Wave tile = 16 rows x 128 cols (8 col-tiles of mfma_f32_16x16x32_bf16).
// ---------------------------------------------------------------------------
__global__ __launch_bounds__(256) void gemm_kernel(const float* __restrict__ x,
                                                   const unsigned short* __restrict__ wbf,
                                                   unsigned* __restrict__ xwb) {
    int wave = threadIdx.x >> 6;
    int lane = threadIdx.x & 63;
    int m = lane & 15;
    int q = lane >> 4;
    int r0 = blockIdx.x * 64 + wave * 16;

    int arow = r0 + m;
    if (arow >= N_NODES) arow = N_NODES - 1;     // clamp loads; stores guarded
    const float* xr = x + (long long)arow * IN_CH + q * 8;

    f4 acc[8];
#pragma unroll
    for (int ct = 0; ct < 8; ++ct) acc[ct] = (f4){0.f, 0.f, 0.f, 0.f};

#pragma unroll
    for (int ks = 0; ks < 8; ++ks) {             // k0 = ks*32
        float4 xa = *(const float4*)(xr + ks * 32);
        float4 xb = *(const float4*)(xr + ks * 32 + 4);
        bf8 a;
        a[0] = (short)f2bf(xa.x); a[1] = (short)f2bf(xa.y);
        a[2] = (short)f2bf(xa.z); a[3] = (short)f2bf(xa.w);
        a[4] = (short)f2bf(xb.x); a[5] = (short)f2bf(xb.y);
        a[6] = (short)f2bf(xb.z); a[7] = (short)f2bf(xb.w);
#pragma unroll
        for (int ct = 0; ct < 8; ++ct) {
            uv4 u = *(const uv4*)&wbf[(ct * 16 + m) * 256 + ks * 32 + q * 8];
            bf8 b = __builtin_bit_cast(bf8, u);
            acc[ct] = __builtin_amdgcn_mfma_f32_16x16x32_bf16(a, b, acc[ct], 0, 0, 0);
        }
    }

#pragma unroll
    for (int ct = 0; ct < 8; ++ct) {
#pragma unroll
        for (int r = 0; r < 4; ++r) {
            float v = acc[ct][r];
            float p = __shfl_xor(v, 1, 64);
            unsigned mine = f2bf(v), oth = f2bf(p);
            if (!(m & 1)) {
                int row = r0 + q * 4 + r;
                if (row < N_NODES)
                    xwb[row * 64 + ct * 8 + (m >> 1)] = mine | (oth << 16);
            }
        }
    }
}

// ---------------------------------------------------------------------------
// Stage-1 histogram: per-chunk LDS histogram over 3125 buckets; LDS atomics
// only. Writes cntT[chunk][bucket] (chunk-major -> fully coalesced stores).
// ---------------------------------------------------------------------------
__global__ __launch_bounds__(1024) void h1_kernel(const int* __restrict__ src,
                                                  int* __restrict__ cntT) {
    __shared__ int lc[NBIN];
    int tid = threadIdx.x;
    for (int i = tid; i < NBIN; i += 1024) lc[i] = 0;
    __syncthreads();
#pragma unroll
    for (int k = 0; k < EPB1 / 4096; ++k) {
        int i = blockIdx.x * EPB1 + k * 4096 + tid * 4;
        if (i < N_EDGES) {                       // i,N_EDGES both mult of 4
            int4 s = *(const int4*)&src[i];
            atomicAdd(&lc[s.x >> BSH], 1);
            atomicAdd(&lc[s.y >> BSH], 1);
            atomicAdd(&lc[s.z >> BSH], 1);
            atomicAdd(&lc[s.w >> BSH], 1);
        }
    }
    __syncthreads();
    for (int i = tid; i < NBIN; i += 1024)
        cntT[blockIdx.x * NBIN + i] = lc[i];
}

// ---------------------------------------------------------------------------
// Tiled LDS transpose: in[R][C] -> out[C][R]. grid = (ceil(C/32), ceil(R/32)),
// block = 256 (32x8, 4-row loop). Turns the stride-1568B count/base accesses
// into coalesced ones on both producer and consumer sides.
// ---------------------------------------------------------------------------
__global__ __launch_bounds__(256) void transpose_kernel(const int* __restrict__ in,
                                                        int* __restrict__ out,
                                                        int R, int C) {
    __shared__ int t[32][33];
    int tx = threadIdx.x & 31, ty0 = threadIdx.x >> 5;
    int c0 = blockIdx.x * 32, r0 = blockIdx.y * 32;
#pragma unroll
    for (int i = 0; i < 4; ++i) {
        int r = r0 + ty0 + i * 8, c = c0 + tx;
        t[ty0 + i * 8][tx] = (r < R && c < C) ? in[r * C + c] : 0;
    }
    __syncthreads();
#pragma unroll
    for (int i = 0; i < 4; ++i) {
        int c = c0 + ty0 + i * 8, r = r0 + tx;
        if (c < C && r < R) out[c * R + r] = t[tx][ty0 + i * 8];
    }
}

// ---------------------------------------------------------------------------
// 3-kernel exclusive scan over NS1 = 1,225,000 counts (bucket-major) -> rpA.
// ---------------------------------------------------------------------------
__global__ __launch_bounds__(256) void scan_s1(const int* __restrict__ cnt,
                                               int* __restrict__ bsum) {
    __shared__ int wsum[4];
    int tid = threadIdx.x, lane = tid & 63, wid = tid >> 6;
    int acc = 0;
#pragma unroll
    for (int k = 0; k < SCAN_CHUNK / 1024; ++k) {
        int i0 = blockIdx.x * SCAN_CHUNK + k * 1024 + tid * 4;
        if (i0 < NS1) {                          // NS1 mult of 4 -> full int4 ok
            int4 v = *(const int4*)&cnt[i0];
            acc += v.x + v.y + v.z + v.w;
        }
    }
#pragma unroll
    for (int off = 32; off; off >>= 1) acc += __shfl_down(acc, off, 64);
    if (lane == 0) wsum[wid] = acc;
    __syncthreads();
    if (tid == 0) bsum[blockIdx.x] = wsum[0] + wsum[1] + wsum[2] + wsum[3];
}

__global__ __launch_bounds__(256) void scan_s2(int* __restrict__ bsum,
                                               int* __restrict__ rpA,
                                               int* __restrict__ rpn) {
    __shared__ int wsum[4];
    int tid = threadIdx.x, lane = tid & 63, wid = tid >> 6;
    int v = (tid < NBLK_S1) ? bsum[tid] : 0;
    int s = v;
#pragma unroll
    for (int off = 1; off < 64; off <<= 1) {
        int t = __shfl_up(s, off, 64);
        if (lane >= off) s += t;
    }
    if (lane == 63) wsum[wid] = s;
    __syncthreads();
    int w0 = wsum[0], w1 = wsum[1], w2 = wsum[2], w3 = wsum[3];
    int woff = (wid > 0 ? w0 : 0) + (wid > 1 ? w1 : 0) + (wid > 2 ? w2 : 0);
    if (tid < NBLK_S1) bsum[tid] = woff + s - v;
    if (tid == 0) {
        int tot = w0 + w1 + w2 + w3;             // == N_EDGES
        rpA[NS1] = tot;
        rpn[N_NODES] = tot;
    }
}

__global__ __launch_bounds__(256) void scan_s3(const int* __restrict__ cnt,
                                               const int* __restrict__ bsum,
                                               int* __restrict__ rpA) {
    __shared__ int wsum[4];
    int tid = threadIdx.x, lane = tid & 63, wid = tid >> 6;
    int carry = bsum[blockIdx.x];
#pragma unroll
    for (int k = 0; k < SCAN_CHUNK / 1024; ++k) {
        int i0 = blockIdx.x * SCAN_CHUNK + k * 1024 + tid * 4;
        int4 v = make_int4(0, 0, 0, 0);
        if (i0 < NS1) v = *(const int4*)&cnt[i0];
        int sum4 = v.x + v.y + v.z + v.w;
        int s = sum4;
#pragma unroll
        for (int off = 1; off < 64; off <<= 1) {
            int t = __shfl_up(s, off, 64);
            if (lane >= off) s += t;
        }
        if (lane == 63) wsum[wid] = s;
        __syncthreads();
        int w0 = wsum[0], w1 = wsum[1], w2 = wsum[2], w3 = wsum[3];
        int woff = (wid > 0 ? w0 : 0) + (wid > 1 ? w1 : 0) + (wid > 2 ? w2 : 0);
        int excl = carry + woff + (s - sum4);
        if (i0 < NS1)
            *(int4*)&rpA[i0] = make_int4(excl, excl + v.x, excl + v.x + v.y,
                                         excl + v.x + v.y + v.z);
        carry += w0 + w1 + w2 + w3;
        __syncthreads();
    }
}

// ---------------------------------------------------------------------------
// Stage-1 scatter, deterministic bases: chunk c loads its per-bucket bases
// from rpT (chunk-major -> coalesced), ranks edges with LDS atomicAdd,
// stores records to its private (bucket,chunk) segments. No device atomics.
// Record: x = dst | (src&31)<<17   (dst < 2^17), y = val bits.
// ---------------------------------------------------------------------------
__global__ __launch_bounds__(1024) void b1_kernel(const int* __restrict__ src,
                                                  const int* __restrict__ dst,
                                                  const float* __restrict__ val,
                                                  const int* __restrict__ rpT,
                                                  int2* __restrict__ p1) {
    __shared__ int lcur[NBIN];
    int tid = threadIdx.x;
    for (int i = tid; i < NBIN; i += 1024)
        lcur[i] = rpT[blockIdx.x * NBIN + i];
    __syncthreads();
#pragma unroll
    for (int k = 0; k < EPB1 / 4096; ++k) {
        int i = blockIdx.x * EPB1 + k * 4096 + tid * 4;
        if (i < N_EDGES) {
            int4   s = *(const int4*)&src[i];
            int4   d = *(const int4*)&dst[i];
            float4 v = *(const float4*)&val[i];
            int p;
            p = atomicAdd(&lcur[s.x >> BSH], 1);
            p1[p] = make_int2(d.x | ((s.x & (BN - 1)) << 17), __float_as_int(v.x));
            p = atomicAdd(&lcur[s.y >> BSH], 1);
            p1[p] = make_int2(d.y | ((s.y & (BN - 1)) << 17), __float_as_int(v.y));
            p = atomicAdd(&lcur[s.z >> BSH], 1);
            p1[p] = make_int2(d.z | ((s.z & (BN - 1)) << 17), __float_as_int(v.z));
            p = atomicAdd(&lcur[s.w >> BSH], 1);
            p1[p] = make_int2(d.w | ((s.w & (BN - 1)) << 17), __float_as_int(v.w));
        }
    }
}

// ---------------------------------------------------------------------------
// Stage-2: one block per 32-node bucket. Stage the bucket's records in LDS
// on the histogram pass (single global read; fallback to 2-read if >SCAP),
// LDS 32-bin hist + wave scan, scatter to final node-major CSR positions.
// Emits rpn[] for free.
// ---------------------------------------------------------------------------
__global__ __launch_bounds__(256) void sortf_kernel(const int2* __restrict__ p1,
                                                    const int* __restrict__ rpA,
                                                    int2* __restrict__ packed,
                                                    int* __restrict__ rpn) {
    __shared__ int  lcnt[BN];
    __shared__ int  lcur[BN];
    __shared__ int2 sbuf[SCAP];
    int b = blockIdx.x, tid = threadIdx.x;
    int beg = rpA[b * NBLK1];
    int end = rpA[(b + 1) * NBLK1];              // b==NBIN-1 hits rpA[NS1]
    int n = end - beg;

    if (tid < BN) lcnt[tid] = 0;
    __syncthreads();

    if (n <= SCAP) {
        for (int e = tid; e < n; e += 256) {
            int2 q = p1[beg + e];
            sbuf[e] = q;
            atomicAdd(&lcnt[(q.x >> 17) & (BN - 1)], 1);
        }
    } else {
        for (int e = beg + tid; e < end; e += 256)
            atomicAdd(&lcnt[(p1[e].x >> 17) & (BN - 1)], 1);
    }
    __syncthreads();

    if (tid < BN) {                              // wave 0: scan 32 counts
        int c = lcnt[tid];
        int v = c;
#pragma unroll
        for (int off = 1; off < BN; off <<= 1) {
            int t = __shfl_up(v, off, 64);
            if (tid >= off) v += t;
        }
        int excl = beg + v - c;
        lcur[tid] = excl;
        rpn[b * BN + tid] = excl;                // NBIN*BN == N_NODES exactly
    }
    __syncthreads();

    if (n <= SCAP) {
        for (int e = tid; e < n; e += 256) {
            int2 q = sbuf[e];
            int p = atomicAdd(&lcur[(q.x >> 17) & (BN - 1)], 1);
            packed[p] = make_int2(q.x & 0x1FFFF, q.y);
        }
    } else {
        for (int e = beg + tid; e < end; e += 256) {
            int2 q = p1[e];
            int p = atomicAdd(&lcur[(q.x >> 17) & (BN - 1)], 1);
            packed[p] = make_int2(q.x & 0x1FFFF, q.y);
        }
    }
}

// ---------------------------------------------------------------------------
// Aggregate: one node per wave. Lanes cooperatively load the node's packed
// records (coalesced, 64/load), broadcast each edge via v_readlane (SGPR dst
// -> scalar-base gather addressing), gathers issued in independent batches
// of 8 for MLP. fp32 accumulate, 2 channels per lane.
// ---------------------------------------------------------------------------
__global__ __launch_bounds__(256) void aggregate_kernel(const int* __restrict__ rp,
                                                        const int2* __restrict__ packed,
                                                        const unsigned* __restrict__ xwb,
                                                        const float* __restrict__ bias,
                                                        float* __restrict__ out) {
    int node = blockIdx.x * 4 + (threadIdx.x >> 6);
    int lane = threadIdx.x & 63;
    float2 acc = *(const float2*)&bias[lane * 2];

    int beg = rp[node];
    int end = rp[node + 1];
    for (int t = beg; t < end; t += 64) {
        int2 rec = make_int2(0, 0);              // dst=0, val=+0.0f (safe pad)
        if (t + lane < end) rec = packed[t + lane];
        int cnt = end - t; if (cnt > 64) cnt = 64;
        int cnt8 = (cnt + 7) & ~7;               // pad lanes contribute 0
        for (int j = 0; j < cnt8; j += 8) {
            unsigned u[8]; float vv[8];
#pragma unroll
            for (int k = 0; k < 8; ++k) {
                int d  = __builtin_amdgcn_readlane(rec.x, j + k);
                int vb = __builtin_amdgcn_readlane(rec.y, j + k);
                vv[k] = __int_as_float(vb);
                u[k]  = xwb[d * 64 + lane];
            }
#pragma unroll
            for (int k = 0; k < 8; ++k) {
                acc.x += vv[k] * __uint_as_float(u[k] << 16);
                acc.y += vv[k] * __uint_as_float(u[k] & 0xffff0000u);
            }
        }
    }
    *(float2*)&out[(long long)node * OUT_CH + lane * 2] = acc;
}

extern "C" void kernel_launch(void* const* d_in, const int* in_sizes, int n_in,
                              void* d_out, int out_size, void* d_ws, size_t ws_size,
                              hipStream_t stream) {
    const float* x     = (const float*)d_in[0];
    const int*   esrc  = (const int*)d_in[1];
    const int*   edst  = (const int*)d_in[2];
    const float* evals = (const float*)d_in[3];
    const float* w     = (const float*)d_in[4];
    const float* bias  = (const float*)d_in[5];
    float* out = (float*)d_out;

    char* ws = (char*)d_ws;
    unsigned*       xwb    = (unsigned*)      (ws + OFF_XWB);
    unsigned short* wbf    = (unsigned short*)(ws + OFF_WBF);
    int*            cntT   = (int*)           (ws + OFF_CNTT);
    int*            cntA   = (int*)           (ws + OFF_CNTA);
    int*            rpA    = (int*)           (ws + OFF_RPA);
    int*            rpT    = (int*)           (ws + OFF_RPT);
    int*            bsum   = (int*)           (ws + OFF_BS);
    int*            rpn    = (int*)           (ws + OFF_RPN);
    int2*           packed = (int2*)          (ws + OFF_PACKED);
    int2*           p1     = (int2*)          d_out;   // scratch; dead before aggregate

    wcvt_kernel<<<128, 256, 0, stream>>>(w, wbf);
    gemm_kernel<<<(N_NODES + 63) / 64, 256, 0, stream>>>(x, wbf, xwb);
    h1_kernel<<<NBLK1, 1024, 0, stream>>>(esrc, cntT);
    transpose_kernel<<<dim3((NBIN + 31) / 32, (NBLK1 + 31) / 32), 256, 0, stream>>>(
        cntT, cntA, NBLK1, NBIN);                       // [392][3125] -> [3125][392]
    scan_s1<<<NBLK_S1, 256, 0, stream>>>(cntA, bsum);
    scan_s2<<<1, 256, 0, stream>>>(bsum, rpA, rpn);
    scan_s3<<<NBLK_S1, 256, 0, stream>>>(cntA, bsum, rpA);
    transpose_kernel<<<dim3((NBLK1 + 31) / 32, (NBIN + 31) / 32), 256, 0, stream>>>(
        rpA, rpT, NBIN, NBLK1);                         // [3125][392] -> [392][3125]
    b1_kernel<<<NBLK1, 1024, 0, stream>>>(esrc, edst, evals, rpT, p1);
    sortf_kernel<<<NBIN, 256, 0, stream>>>(p1, rpA, packed, rpn);
    aggregate_kernel<<<N_NODES / 4, 256, 0, stream>>>(rpn, packed, xwb, bias, out);
}